// Round 1
// baseline (1480.239 us; speedup 1.0000x reference)
//
#include <hip/hip_runtime.h>
#include <math.h>

// ---------------------------------------------------------------------------
// GCN autoencoder: 4 layers (12->16->8->16->12), N=200K nodes, E=5M edges.
// Layer L: xl = h @ W_L ; agg = scatter_add(xl[src]*dis[src]*dis[dst], dst)
//          + self-loop xl[i]*dis[i]^2 ; h_next = act(agg + b_L)
// act: relu (L1), none (L2), relu (L3), sigmoid (L4, in final kernel).
// The bias+activation epilogue of layer L is fused into the transform of
// layer L+1, so agg buffers never need a separate pass.
// ---------------------------------------------------------------------------

__global__ void deg_kernel(const int* __restrict__ dst, int* __restrict__ deg, int E) {
    int e = blockIdx.x * blockDim.x + threadIdx.x;
    if (e < E) atomicAdd(&deg[dst[e]], 1);
}

__global__ void dis_kernel(const int* __restrict__ deg, float* __restrict__ dis, int N) {
    int i = blockIdx.x * blockDim.x + threadIdx.x;
    if (i < N) {
        // +1 for the self-loop; deg >= 1 always, so no zero-guard needed.
        dis[i] = 1.0f / sqrtf((float)(deg[i] + 1));
    }
}

// PREACT: 0 = raw input (layer 1, no bias), 1 = bias + relu, 2 = bias only
template <int IN, int OUT, int PREACT>
__global__ __launch_bounds__(256) void transform_kernel(
    const float* __restrict__ hin, const float* __restrict__ bias_prev,
    const float* __restrict__ W, const float* __restrict__ dis,
    float* __restrict__ xl, float* __restrict__ agg, int N) {
    __shared__ float sW[IN * OUT];
    __shared__ float sB[IN];
    for (int t = threadIdx.x; t < IN * OUT; t += blockDim.x) sW[t] = W[t];
    if (PREACT != 0) {
        for (int t = threadIdx.x; t < IN; t += blockDim.x) sB[t] = bias_prev[t];
    }
    __syncthreads();
    int i = blockIdx.x * blockDim.x + threadIdx.x;
    if (i >= N) return;

    float h[IN];
#pragma unroll
    for (int k = 0; k < IN; k++) {
        float v = hin[i * IN + k];
        if (PREACT != 0) {
            v += sB[k];
            if (PREACT == 1) v = fmaxf(v, 0.0f);
        }
        h[k] = v;
    }
    float d = dis[i];
    float d2 = d * d;
#pragma unroll
    for (int f = 0; f < OUT; f++) {
        float acc = 0.0f;
#pragma unroll
        for (int k = 0; k < IN; k++) acc = fmaf(h[k], sW[k * OUT + f], acc);
        xl[i * OUT + f] = acc;
        agg[i * OUT + f] = acc * d2;  // self-loop term initializes agg
    }
}

// One thread per (edge, feature). F consecutive lanes share an edge, so the
// xl gather and agg atomics land in 1-2 cache lines per edge.
template <int F>
__global__ __launch_bounds__(256) void scatter_kernel(
    const int* __restrict__ src, const int* __restrict__ dst,
    const float* __restrict__ dis, const float* __restrict__ xl,
    float* __restrict__ agg, int E) {
    int idx = blockIdx.x * blockDim.x + threadIdx.x;  // E*F <= 80M < 2^31
    if (idx >= E * F) return;
    int e = idx / F;
    int f = idx - e * F;
    int s = src[e];
    int d = dst[e];
    float w = dis[s] * dis[d];
    atomicAdd(&agg[d * F + f], xl[s * F + f] * w);
}

__global__ void final_kernel(const float* __restrict__ agg,
                             const float* __restrict__ b,
                             float* __restrict__ out, int total, int F) {
    int idx = blockIdx.x * blockDim.x + threadIdx.x;
    if (idx < total) {
        int f = idx % F;
        float v = agg[idx] + b[f];
        out[idx] = 1.0f / (1.0f + expf(-v));
    }
}

static inline size_t align_up(size_t v, size_t a) { return (v + a - 1) & ~(a - 1); }

extern "C" void kernel_launch(void* const* d_in, const int* in_sizes, int n_in,
                              void* d_out, int out_size, void* d_ws, size_t ws_size,
                              hipStream_t stream) {
    const float* x  = (const float*)d_in[0];
    const int*   ei = (const int*)d_in[1];
    const float* W1 = (const float*)d_in[2];
    const float* b1 = (const float*)d_in[3];
    const float* W2 = (const float*)d_in[4];
    const float* b2 = (const float*)d_in[5];
    const float* W3 = (const float*)d_in[6];
    const float* b3 = (const float*)d_in[7];
    const float* W4 = (const float*)d_in[8];
    const float* b4 = (const float*)d_in[9];
    float* out = (float*)d_out;

    const int N = in_sizes[0] / 12;
    const int E = in_sizes[1] / 2;
    const int* src = ei;       // edge_index[0]
    const int* dst = ei + E;   // edge_index[1]

    // Workspace carve-up
    char* ws = (char*)d_ws;
    size_t off = 0;
    int* deg = (int*)(ws + off);      off = align_up(off + (size_t)N * 4, 256);
    float* dis = (float*)(ws + off);  off = align_up(off + (size_t)N * 4, 256);
    float* xl = (float*)(ws + off);   off = align_up(off + (size_t)N * 16 * 4, 256);
    float* agg_a = (float*)(ws + off); off = align_up(off + (size_t)N * 16 * 4, 256);
    float* agg_b = (float*)(ws + off); off = align_up(off + (size_t)N * 16 * 4, 256);
    (void)ws_size; (void)n_in; (void)out_size;

    const int B = 256;
    auto blocks = [&](long long n) { return (int)((n + B - 1) / B); };

    // Degree + normalization
    hipMemsetAsync(deg, 0, (size_t)N * sizeof(int), stream);
    deg_kernel<<<blocks(E), B, 0, stream>>>(dst, deg, E);
    dis_kernel<<<blocks(N), B, 0, stream>>>(deg, dis, N);

    // Layer 1: x(12) @ W1 -> 16
    transform_kernel<12, 16, 0><<<blocks(N), B, 0, stream>>>(x, nullptr, W1, dis, xl, agg_a, N);
    scatter_kernel<16><<<blocks((long long)E * 16), B, 0, stream>>>(src, dst, dis, xl, agg_a, E);

    // Layer 2: relu(agg_a + b1)(16) @ W2 -> 8
    transform_kernel<16, 8, 1><<<blocks(N), B, 0, stream>>>(agg_a, b1, W2, dis, xl, agg_b, N);
    scatter_kernel<8><<<blocks((long long)E * 8), B, 0, stream>>>(src, dst, dis, xl, agg_b, E);

    // Layer 3: (agg_b + b2)(8) @ W3 -> 16   (no relu after layer 2)
    transform_kernel<8, 16, 2><<<blocks(N), B, 0, stream>>>(agg_b, b2, W3, dis, xl, agg_a, N);
    scatter_kernel<16><<<blocks((long long)E * 16), B, 0, stream>>>(src, dst, dis, xl, agg_a, E);

    // Layer 4: relu(agg_a + b3)(16) @ W4 -> 12
    transform_kernel<16, 12, 1><<<blocks(N), B, 0, stream>>>(agg_a, b3, W4, dis, xl, agg_b, N);
    scatter_kernel<12><<<blocks((long long)E * 12), B, 0, stream>>>(src, dst, dis, xl, agg_b, E);

    // Epilogue: sigmoid(agg_b + b4) -> out
    final_kernel<<<blocks((long long)N * 12), B, 0, stream>>>(agg_b, b4, out, N * 12, 12);
}

// Round 2
// 1243.478 us; speedup vs baseline: 1.1904x; 1.1904x over previous
//
#include <hip/hip_runtime.h>
#include <math.h>

// ---------------------------------------------------------------------------
// GCN autoencoder: 4 layers (12->16->8->16->12), N=200K nodes, E=5M edges.
//
// Round 2: replace atomic scatter (322 MB HBM RMW traffic per layer) with a
// per-launch CSR build + pull-mode gather. All per-layer heavy traffic is now
// read-only (cacheable) or streaming.
//
//   xls[i] = (h[i] @ W) * dis[i]                        (transform kernel)
//   agg[i] = dis[i] * ( xls[i] + sum_{e in in(i)} xls[col[e]] )   (gather)
//   h_next = act(agg + b)   -- fused into next transform / final kernel
// ---------------------------------------------------------------------------

__global__ void deg_kernel(const int* __restrict__ dst, int* __restrict__ deg, int E) {
    int e = blockIdx.x * blockDim.x + threadIdx.x;
    if (e < E) atomicAdd(&deg[dst[e]], 1);
}

__global__ void dis_kernel(const int* __restrict__ deg, float* __restrict__ dis, int N) {
    int i = blockIdx.x * blockDim.x + threadIdx.x;
    if (i < N) {
        // +1 for the self-loop; deg+1 >= 1 always.
        dis[i] = 1.0f / sqrtf((float)(deg[i] + 1));
    }
}

// --- exclusive scan over deg -> row_ptr (3-kernel classic) ------------------
__global__ __launch_bounds__(256) void scan1_kernel(const int* __restrict__ deg,
                                                    int* __restrict__ row_ptr,
                                                    int* __restrict__ bsums, int N) {
    __shared__ int s[256];
    int i = blockIdx.x * 256 + threadIdx.x;
    int v = (i < N) ? deg[i] : 0;
    s[threadIdx.x] = v;
    __syncthreads();
#pragma unroll
    for (int off = 1; off < 256; off <<= 1) {
        int t = (threadIdx.x >= (unsigned)off) ? s[threadIdx.x - off] : 0;
        __syncthreads();
        s[threadIdx.x] += t;
        __syncthreads();
    }
    if (i < N) row_ptr[i] = s[threadIdx.x] - v;  // exclusive within block
    if (threadIdx.x == 255) bsums[blockIdx.x] = s[255];
}

__global__ __launch_bounds__(1024) void scan2_kernel(int* __restrict__ data, int n) {
    __shared__ int s[1024];
    int carry = 0;
    for (int base = 0; base < n; base += 1024) {
        int i = base + threadIdx.x;
        int v = (i < n) ? data[i] : 0;
        s[threadIdx.x] = v;
        __syncthreads();
        for (int off = 1; off < 1024; off <<= 1) {
            int t = (threadIdx.x >= (unsigned)off) ? s[threadIdx.x - off] : 0;
            __syncthreads();
            s[threadIdx.x] += t;
            __syncthreads();
        }
        if (i < n) data[i] = carry + s[threadIdx.x] - v;  // exclusive
        int total = s[1023];
        __syncthreads();
        carry += total;
    }
}

__global__ __launch_bounds__(256) void scan3_kernel(int* __restrict__ row_ptr,
                                                    const int* __restrict__ bsums,
                                                    int* __restrict__ cursor,
                                                    int N, int E) {
    int i = blockIdx.x * 256 + threadIdx.x;
    if (i < N) {
        int v = row_ptr[i] + bsums[blockIdx.x];
        row_ptr[i] = v;
        cursor[i] = v;
    }
    if (i == 0) row_ptr[N] = E;
}

// Scatter src ids into CSR order: 1 int atomic + 1 int write per edge.
__global__ __launch_bounds__(256) void build_kernel(const int* __restrict__ src,
                                                    const int* __restrict__ dst,
                                                    int* __restrict__ cursor,
                                                    int* __restrict__ col, int E) {
    int e = blockIdx.x * blockDim.x + threadIdx.x;
    if (e < E) {
        int pos = atomicAdd(&cursor[dst[e]], 1);
        col[pos] = src[e];
    }
}

// PREACT: 0 = raw input (layer 1), 1 = bias + relu, 2 = bias only
template <int IN, int OUT, int PREACT>
__global__ __launch_bounds__(256) void transform_kernel(
    const float* __restrict__ hin, const float* __restrict__ bias_prev,
    const float* __restrict__ W, const float* __restrict__ dis,
    float* __restrict__ xls, int N) {
    __shared__ float sW[IN * OUT];
    __shared__ float sB[IN];
    for (int t = threadIdx.x; t < IN * OUT; t += blockDim.x) sW[t] = W[t];
    if (PREACT != 0) {
        for (int t = threadIdx.x; t < IN; t += blockDim.x) sB[t] = bias_prev[t];
    }
    __syncthreads();
    int i = blockIdx.x * blockDim.x + threadIdx.x;
    if (i >= N) return;

    float h[IN];
#pragma unroll
    for (int k = 0; k < IN; k++) {
        float v = hin[i * IN + k];
        if (PREACT != 0) {
            v += sB[k];
            if (PREACT == 1) v = fmaxf(v, 0.0f);
        }
        h[k] = v;
    }
    float d = dis[i];
#pragma unroll
    for (int f = 0; f < OUT; f++) {
        float acc = 0.0f;
#pragma unroll
        for (int k = 0; k < IN; k++) acc = fmaf(h[k], sW[k * OUT + f], acc);
        xls[i * OUT + f] = acc * d;  // pre-scaled by dis[i]
    }
}

// Pull-mode aggregation: thread (i,f) sums its node's in-edge segment.
// F threads of one node read the same col[e] (broadcast) and 4F contiguous
// bytes of xls (one cache-line-ish segment). No atomics anywhere.
template <int F>
__global__ __launch_bounds__(256) void gather_kernel(
    const int* __restrict__ row_ptr, const int* __restrict__ col,
    const float* __restrict__ dis, const float* __restrict__ xls,
    float* __restrict__ agg, int N) {
    int idx = blockIdx.x * blockDim.x + threadIdx.x;
    if (idx >= N * F) return;
    int i = idx / F;
    int f = idx - i * F;
    int beg = row_ptr[i];
    int end = row_ptr[i + 1];
    float acc = xls[i * F + f];  // self-loop term
    for (int e = beg; e < end; e++) {
        int c = col[e];
        acc += xls[c * F + f];
    }
    agg[i * F + f] = acc * dis[i];
}

__global__ void final_kernel(const float* __restrict__ agg,
                             const float* __restrict__ b,
                             float* __restrict__ out, int total, int F) {
    int idx = blockIdx.x * blockDim.x + threadIdx.x;
    if (idx < total) {
        int f = idx % F;
        float v = agg[idx] + b[f];
        out[idx] = 1.0f / (1.0f + expf(-v));
    }
}

static inline size_t align_up(size_t v, size_t a) { return (v + a - 1) & ~(a - 1); }

extern "C" void kernel_launch(void* const* d_in, const int* in_sizes, int n_in,
                              void* d_out, int out_size, void* d_ws, size_t ws_size,
                              hipStream_t stream) {
    const float* x  = (const float*)d_in[0];
    const int*   ei = (const int*)d_in[1];
    const float* W1 = (const float*)d_in[2];
    const float* b1 = (const float*)d_in[3];
    const float* W2 = (const float*)d_in[4];
    const float* b2 = (const float*)d_in[5];
    const float* W3 = (const float*)d_in[6];
    const float* b3 = (const float*)d_in[7];
    const float* W4 = (const float*)d_in[8];
    const float* b4 = (const float*)d_in[9];
    float* out = (float*)d_out;

    const int N = in_sizes[0] / 12;
    const int E = in_sizes[1] / 2;
    const int* src = ei;       // edge_index[0]
    const int* dst = ei + E;   // edge_index[1]

    const int B = 256;
    const int nb = (N + B - 1) / B;  // scan blocking

    // Workspace carve-up (~50 MB)
    char* ws = (char*)d_ws;
    size_t off = 0;
    int* deg = (int*)(ws + off);       off = align_up(off + (size_t)N * 4, 256);
    float* dis = (float*)(ws + off);   off = align_up(off + (size_t)N * 4, 256);
    int* row_ptr = (int*)(ws + off);   off = align_up(off + (size_t)(N + 1) * 4, 256);
    int* bsums = (int*)(ws + off);     off = align_up(off + (size_t)nb * 4, 256);
    int* col = (int*)(ws + off);       off = align_up(off + (size_t)E * 4, 256);
    float* xls = (float*)(ws + off);   off = align_up(off + (size_t)N * 16 * 4, 256);
    float* agg = (float*)(ws + off);   off = align_up(off + (size_t)N * 16 * 4, 256);
    int* cursor = deg;  // deg is dead after scan1; reuse as CSR cursor
    (void)ws_size; (void)n_in; (void)out_size;

    auto blocks = [&](long long n) { return (int)((n + B - 1) / B); };

    // --- CSR build -------------------------------------------------------
    hipMemsetAsync(deg, 0, (size_t)N * sizeof(int), stream);
    deg_kernel<<<blocks(E), B, 0, stream>>>(dst, deg, E);
    dis_kernel<<<blocks(N), B, 0, stream>>>(deg, dis, N);
    scan1_kernel<<<nb, B, 0, stream>>>(deg, row_ptr, bsums, N);
    scan2_kernel<<<1, 1024, 0, stream>>>(bsums, nb);
    scan3_kernel<<<nb, B, 0, stream>>>(row_ptr, bsums, cursor, N, E);
    build_kernel<<<blocks(E), B, 0, stream>>>(src, dst, cursor, col, E);

    // --- Layer 1: x(12) @ W1 -> 16 --------------------------------------
    transform_kernel<12, 16, 0><<<blocks(N), B, 0, stream>>>(x, nullptr, W1, dis, xls, N);
    gather_kernel<16><<<blocks((long long)N * 16), B, 0, stream>>>(row_ptr, col, dis, xls, agg, N);

    // --- Layer 2: relu(agg + b1)(16) @ W2 -> 8 ---------------------------
    transform_kernel<16, 8, 1><<<blocks(N), B, 0, stream>>>(agg, b1, W2, dis, xls, N);
    gather_kernel<8><<<blocks((long long)N * 8), B, 0, stream>>>(row_ptr, col, dis, xls, agg, N);

    // --- Layer 3: (agg + b2)(8) @ W3 -> 16  (no relu after layer 2) ------
    transform_kernel<8, 16, 2><<<blocks(N), B, 0, stream>>>(agg, b2, W3, dis, xls, N);
    gather_kernel<16><<<blocks((long long)N * 16), B, 0, stream>>>(row_ptr, col, dis, xls, agg, N);

    // --- Layer 4: relu(agg + b3)(16) @ W4 -> 12 --------------------------
    transform_kernel<16, 12, 1><<<blocks(N), B, 0, stream>>>(agg, b3, W4, dis, xls, N);
    gather_kernel<12><<<blocks((long long)N * 12), B, 0, stream>>>(row_ptr, col, dis, xls, agg, N);

    // --- Epilogue: sigmoid(agg + b4) -> out ------------------------------
    final_kernel<<<blocks((long long)N * 12), B, 0, stream>>>(agg, b4, out, N * 12, 12);
}

// Round 3
// 773.774 us; speedup vs baseline: 1.9130x; 1.6070x over previous
//
#include <hip/hip_runtime.h>
#include <math.h>

// ---------------------------------------------------------------------------
// GCN autoencoder: 4 layers (12->16->8->16->12), N=200K nodes, E=5M edges.
//
// Round 3: the CSR build's random 4B writes cost 309 MB of line write-allocate
// traffic (440 us) and deg's random atomics a similar amount. Replace both
// with a bucketed counting sort (buckets of 256 dst nodes):
//   hist -> bscan -> bin (LDS-aggregated, run-contiguous record writes)
//   -> csr_bucket (one WG per bucket: LDS degree count + scan + LDS col
//      staging, all global writes sequential; also emits row_ptr and dis).
// Per-layer compute unchanged:
//   xls[i] = (h[i] @ W) * dis[i]
//   agg[i] = dis[i] * ( xls[i] + sum_{e in in(i)} xls[col[e]] )
// ---------------------------------------------------------------------------

#define NODES_PER_BUCKET 256   // bucket id = dst >> 8
#define MAX_NB 1024            // supports N <= 262144
#define BIN_CHUNK 16384        // edges per workgroup in bin_kernel
#define MAXB 9216              // LDS col staging capacity (avg bucket ~6400)

__global__ __launch_bounds__(256) void hist_kernel(const int* __restrict__ dst,
                                                   int* __restrict__ bucket_cnt,
                                                   int E, int NB) {
    __shared__ int h[MAX_NB];
    for (int t = threadIdx.x; t < NB; t += 256) h[t] = 0;
    __syncthreads();
    int stride = gridDim.x * 256;
    for (int e = blockIdx.x * 256 + threadIdx.x; e < E; e += stride)
        atomicAdd(&h[dst[e] >> 8], 1);
    __syncthreads();
    for (int t = threadIdx.x; t < NB; t += 256)
        if (h[t]) atomicAdd(&bucket_cnt[t], h[t]);
}

__global__ __launch_bounds__(1024) void bscan_kernel(const int* __restrict__ bucket_cnt,
                                                     int* __restrict__ bucket_ptr,
                                                     int* __restrict__ bucket_cur,
                                                     int* __restrict__ row_ptr,
                                                     int NB, int N, int E) {
    __shared__ int s[1024];
    int v = (threadIdx.x < (unsigned)NB) ? bucket_cnt[threadIdx.x] : 0;
    s[threadIdx.x] = v;
    __syncthreads();
    for (int off = 1; off < 1024; off <<= 1) {
        int t = (threadIdx.x >= (unsigned)off) ? s[threadIdx.x - off] : 0;
        __syncthreads();
        s[threadIdx.x] += t;
        __syncthreads();
    }
    int excl = s[threadIdx.x] - v;
    if (threadIdx.x < (unsigned)NB) {
        bucket_ptr[threadIdx.x] = excl;
        bucket_cur[threadIdx.x] = excl;
    }
    if (threadIdx.x == 0) { bucket_ptr[NB] = E; row_ptr[N] = E; }
}

// Each workgroup: LDS histogram of its chunk, ONE global atomic per touched
// bucket to reserve a contiguous run, then append 4B packed records
// ((src<<8)|local_dst). Run-contiguous writes fill cache lines.
__global__ __launch_bounds__(256) void bin_kernel(const int* __restrict__ src,
                                                  const int* __restrict__ dst,
                                                  int* __restrict__ bucket_cur,
                                                  unsigned int* __restrict__ binned,
                                                  int E, int NB) {
    __shared__ int h[MAX_NB];
    __shared__ int base[MAX_NB];
    int cbeg = blockIdx.x * BIN_CHUNK;
    int cend = min(cbeg + BIN_CHUNK, E);
    for (int t = threadIdx.x; t < NB; t += 256) h[t] = 0;
    __syncthreads();
    for (int e = cbeg + threadIdx.x; e < cend; e += 256)
        atomicAdd(&h[dst[e] >> 8], 1);
    __syncthreads();
    for (int t = threadIdx.x; t < NB; t += 256) {
        int c = h[t];
        base[t] = c ? atomicAdd(&bucket_cur[t], c) : 0;
    }
    __syncthreads();
    for (int t = threadIdx.x; t < NB; t += 256) h[t] = 0;  // reuse as cursor
    __syncthreads();
    for (int e = cbeg + threadIdx.x; e < cend; e += 256) {
        int d = dst[e];
        int bkt = d >> 8;
        int pos = base[bkt] + atomicAdd(&h[bkt], 1);
        binned[pos] = ((unsigned)src[e] << 8) | (unsigned)(d & 255);
    }
}

// One workgroup per bucket: count per-node degrees in LDS, scan, emit
// row_ptr segment + dis (sequential), scatter src into LDS, flush coalesced.
__global__ __launch_bounds__(256) void csr_bucket_kernel(
    const unsigned int* __restrict__ binned,
    const int* __restrict__ bucket_ptr,
    int* __restrict__ row_ptr, float* __restrict__ dis,
    int* __restrict__ col, int N) {
    __shared__ int cnt[256];
    __shared__ int cur[256];
    __shared__ int colbuf[MAXB];
    int b = blockIdx.x;
    int nbase = b << 8;
    int nlocal = min(256, N - nbase);
    int beg = bucket_ptr[b];
    int end = bucket_ptr[b + 1];
    int bsize = end - beg;

    cnt[threadIdx.x] = 0;
    __syncthreads();
    for (int k = threadIdx.x; k < bsize; k += 256)
        atomicAdd(&cnt[binned[beg + k] & 255u], 1);
    __syncthreads();
    int v = cnt[threadIdx.x];
    cur[threadIdx.x] = v;
    __syncthreads();
    for (int off = 1; off < 256; off <<= 1) {
        int t = (threadIdx.x >= (unsigned)off) ? cur[threadIdx.x - off] : 0;
        __syncthreads();
        cur[threadIdx.x] += t;
        __syncthreads();
    }
    int excl = cur[threadIdx.x] - v;
    if ((int)threadIdx.x < nlocal) {
        row_ptr[nbase + threadIdx.x] = beg + excl;
        dis[nbase + threadIdx.x] = 1.0f / sqrtf((float)(v + 1));  // +1 self-loop
    }
    __syncthreads();
    cur[threadIdx.x] = excl;
    __syncthreads();
    if (bsize <= MAXB) {
        for (int k = threadIdx.x; k < bsize; k += 256) {
            unsigned rec = binned[beg + k];
            int pos = atomicAdd(&cur[rec & 255u], 1);
            colbuf[pos] = (int)(rec >> 8);
        }
        __syncthreads();
        for (int k = threadIdx.x; k < bsize; k += 256) col[beg + k] = colbuf[k];
    } else {  // never expected for random input; correct slow path
        for (int k = threadIdx.x; k < bsize; k += 256) {
            unsigned rec = binned[beg + k];
            int pos = atomicAdd(&cur[rec & 255u], 1);
            col[beg + pos] = (int)(rec >> 8);
        }
    }
}

// PREACT: 0 = raw input (layer 1), 1 = bias + relu, 2 = bias only
template <int IN, int OUT, int PREACT>
__global__ __launch_bounds__(256) void transform_kernel(
    const float* __restrict__ hin, const float* __restrict__ bias_prev,
    const float* __restrict__ W, const float* __restrict__ dis,
    float* __restrict__ xls, int N) {
    __shared__ float sW[IN * OUT];
    __shared__ float sB[IN];
    for (int t = threadIdx.x; t < IN * OUT; t += blockDim.x) sW[t] = W[t];
    if (PREACT != 0) {
        for (int t = threadIdx.x; t < IN; t += blockDim.x) sB[t] = bias_prev[t];
    }
    __syncthreads();
    int i = blockIdx.x * blockDim.x + threadIdx.x;
    if (i >= N) return;

    float h[IN];
#pragma unroll
    for (int k = 0; k < IN; k++) {
        float v = hin[i * IN + k];
        if (PREACT != 0) {
            v += sB[k];
            if (PREACT == 1) v = fmaxf(v, 0.0f);
        }
        h[k] = v;
    }
    float d = dis[i];
#pragma unroll
    for (int f = 0; f < OUT; f++) {
        float acc = 0.0f;
#pragma unroll
        for (int k = 0; k < IN; k++) acc = fmaf(h[k], sW[k * OUT + f], acc);
        xls[i * OUT + f] = acc * d;  // pre-scaled by dis[i]
    }
}

// Pull-mode aggregation: thread (i,f) sums its node's in-edge segment.
template <int F>
__global__ __launch_bounds__(256) void gather_kernel(
    const int* __restrict__ row_ptr, const int* __restrict__ col,
    const float* __restrict__ dis, const float* __restrict__ xls,
    float* __restrict__ agg, int N) {
    int idx = blockIdx.x * blockDim.x + threadIdx.x;
    if (idx >= N * F) return;
    int i = idx / F;
    int f = idx - i * F;
    int beg = row_ptr[i];
    int end = row_ptr[i + 1];
    float acc = xls[i * F + f];  // self-loop term
    for (int e = beg; e < end; e++) {
        int c = col[e];
        acc += xls[c * F + f];
    }
    agg[i * F + f] = acc * dis[i];
}

__global__ void final_kernel(const float* __restrict__ agg,
                             const float* __restrict__ b,
                             float* __restrict__ out, int total, int F) {
    int idx = blockIdx.x * blockDim.x + threadIdx.x;
    if (idx < total) {
        int f = idx % F;
        float v = agg[idx] + b[f];
        out[idx] = 1.0f / (1.0f + expf(-v));
    }
}

static inline size_t align_up(size_t v, size_t a) { return (v + a - 1) & ~(a - 1); }

extern "C" void kernel_launch(void* const* d_in, const int* in_sizes, int n_in,
                              void* d_out, int out_size, void* d_ws, size_t ws_size,
                              hipStream_t stream) {
    const float* x  = (const float*)d_in[0];
    const int*   ei = (const int*)d_in[1];
    const float* W1 = (const float*)d_in[2];
    const float* b1 = (const float*)d_in[3];
    const float* W2 = (const float*)d_in[4];
    const float* b2 = (const float*)d_in[5];
    const float* W3 = (const float*)d_in[6];
    const float* b3 = (const float*)d_in[7];
    const float* W4 = (const float*)d_in[8];
    const float* b4 = (const float*)d_in[9];
    float* out = (float*)d_out;

    const int N = in_sizes[0] / 12;
    const int E = in_sizes[1] / 2;
    const int* src = ei;       // edge_index[0]
    const int* dst = ei + E;   // edge_index[1]
    const int NB = (N + NODES_PER_BUCKET - 1) / NODES_PER_BUCKET;  // 782

    // Workspace carve-up (~68 MB)
    char* ws = (char*)d_ws;
    size_t off = 0;
    int* bucket_cnt = (int*)(ws + off);   off = align_up(off + (size_t)NB * 4, 256);
    int* bucket_ptr = (int*)(ws + off);   off = align_up(off + (size_t)(NB + 1) * 4, 256);
    int* bucket_cur = (int*)(ws + off);   off = align_up(off + (size_t)NB * 4, 256);
    int* row_ptr = (int*)(ws + off);      off = align_up(off + (size_t)(N + 1) * 4, 256);
    float* dis = (float*)(ws + off);      off = align_up(off + (size_t)N * 4, 256);
    unsigned int* binned = (unsigned int*)(ws + off); off = align_up(off + (size_t)E * 4, 256);
    int* col = (int*)(ws + off);          off = align_up(off + (size_t)E * 4, 256);
    float* xls = (float*)(ws + off);      off = align_up(off + (size_t)N * 16 * 4, 256);
    float* agg = (float*)(ws + off);      off = align_up(off + (size_t)N * 16 * 4, 256);
    (void)ws_size; (void)n_in; (void)out_size;

    const int B = 256;
    auto blocks = [&](long long n) { return (int)((n + B - 1) / B); };

    // --- CSR build via bucketed counting sort ----------------------------
    hipMemsetAsync(bucket_cnt, 0, (size_t)NB * sizeof(int), stream);
    hist_kernel<<<512, B, 0, stream>>>(dst, bucket_cnt, E, NB);
    bscan_kernel<<<1, 1024, 0, stream>>>(bucket_cnt, bucket_ptr, bucket_cur, row_ptr, NB, N, E);
    bin_kernel<<<(E + BIN_CHUNK - 1) / BIN_CHUNK, B, 0, stream>>>(src, dst, bucket_cur, binned, E, NB);
    csr_bucket_kernel<<<NB, B, 0, stream>>>(binned, bucket_ptr, row_ptr, dis, col, N);

    // --- Layer 1: x(12) @ W1 -> 16 --------------------------------------
    transform_kernel<12, 16, 0><<<blocks(N), B, 0, stream>>>(x, nullptr, W1, dis, xls, N);
    gather_kernel<16><<<blocks((long long)N * 16), B, 0, stream>>>(row_ptr, col, dis, xls, agg, N);

    // --- Layer 2: relu(agg + b1)(16) @ W2 -> 8 ---------------------------
    transform_kernel<16, 8, 1><<<blocks(N), B, 0, stream>>>(agg, b1, W2, dis, xls, N);
    gather_kernel<8><<<blocks((long long)N * 8), B, 0, stream>>>(row_ptr, col, dis, xls, agg, N);

    // --- Layer 3: (agg + b2)(8) @ W3 -> 16  (no relu after layer 2) ------
    transform_kernel<8, 16, 2><<<blocks(N), B, 0, stream>>>(agg, b2, W3, dis, xls, N);
    gather_kernel<16><<<blocks((long long)N * 16), B, 0, stream>>>(row_ptr, col, dis, xls, agg, N);

    // --- Layer 4: relu(agg + b3)(16) @ W4 -> 12 --------------------------
    transform_kernel<16, 12, 1><<<blocks(N), B, 0, stream>>>(agg, b3, W4, dis, xls, N);
    gather_kernel<12><<<blocks((long long)N * 12), B, 0, stream>>>(row_ptr, col, dis, xls, agg, N);

    // --- Epilogue: sigmoid(agg + b4) -> out ------------------------------
    final_kernel<<<blocks((long long)N * 12), B, 0, stream>>>(agg, b4, out, N * 12, 12);
}